// Round 13
// baseline (154.415 us; speedup 1.0000x reference)
//
#include <hip/hip_runtime.h>
#include <hip/hip_bf16.h>
#include <math.h>

#define B    4
#define QL   2048
#define KVL  2048
#define CQ   256
#define CKV  256
#define CH   32
#define NH   8
#define DM   256   // NH*CH
#define KVB  64    // kv strip per iteration
#define NSTRIP (KVL / KVB)   // 32

typedef __attribute__((ext_vector_type(8)))  short short8;   // 8 x bf16 (4 VGPR)
typedef __attribute__((ext_vector_type(4)))  short short4v;  // 4 x bf16
typedef __attribute__((ext_vector_type(4)))  float f32x4;
typedef __attribute__((ext_vector_type(16))) float f32x16;
typedef __attribute__((ext_vector_type(4)))  unsigned int u32x4;

static __device__ __forceinline__ short f2bf(float x) {
    __hip_bfloat16 h = __float2bfloat16(x);
    return __builtin_bit_cast(short, h);
}
static __device__ __forceinline__ float bf2f(short s) {
    unsigned int u = ((unsigned int)(unsigned short)s) << 16;
    return __builtin_bit_cast(float, u);
}
// pack two f32 -> u32 of 2 bf16 (compiler fuses to v_cvt_pk_bf16_f32)
static __device__ __forceinline__ unsigned int pkbf(float lo, float hi) {
    return (unsigned int)(unsigned short)f2bf(lo) |
           ((unsigned int)(unsigned short)f2bf(hi) << 16);
}

// ---------------------------------------------------------------------------
// prep: fp32 -> bf16 copy (8 elems/thread)
// ---------------------------------------------------------------------------
__global__ __launch_bounds__(256) void prep_cvt(
    const float* __restrict__ src, short* __restrict__ dst, int n8)
{
    int i = blockIdx.x * 256 + threadIdx.x;
    if (i >= n8) return;
    const float4* s = (const float4*)src + (size_t)i * 2;
    float4 a = s[0], b = s[1];
    short8 o = { f2bf(a.x), f2bf(a.y), f2bf(a.z), f2bf(a.w),
                 f2bf(b.x), f2bf(b.y), f2bf(b.z), f2bf(b.w) };
    *((short8*)dst + i) = o;
}

// ---------------------------------------------------------------------------
// prep: W [K][N] fp32 -> W^T [N][K] bf16, 32x32 LDS tiles
// ---------------------------------------------------------------------------
__global__ __launch_bounds__(256) void prep_wT(
    const float* __restrict__ w, short* __restrict__ wt, int K, int N)
{
    __shared__ float tile[32][33];
    const int bx = blockIdx.x * 32;            // n
    const int by = blockIdx.y * 32;            // k
    const int tx = threadIdx.x & 31, ty = threadIdx.x >> 5;
    #pragma unroll
    for (int i = 0; i < 32; i += 8)
        tile[ty + i][tx] = w[(size_t)(by + ty + i) * N + bx + tx];
    __syncthreads();
    #pragma unroll
    for (int i = 0; i < 32; i += 8)
        wt[(size_t)(bx + ty + i) * K + by + tx] = f2bf(tile[tx][ty + i]);
}

// ---------------------------------------------------------------------------
// bf16 MFMA GEMM (unchanged): A [M][K] bf16, BT [N][K] bf16.
// 64x64 tile, 4 waves (2x2 of 32x32), BK=32.
// ---------------------------------------------------------------------------
__global__ __launch_bounds__(256) void gemm_mfma(
    const short* __restrict__ A, const short* __restrict__ BT,
    const float* __restrict__ bias, float* __restrict__ outf,
    short* __restrict__ outb,
    int M, int N, int K, float alpha, int mode)
{
    __shared__ __align__(16) short As[64][40];
    __shared__ __align__(16) short Bs[64][40];

    const int t   = threadIdx.x;
    const int m0  = blockIdx.y * 64, n0 = blockIdx.x * 64;
    const int lane = t & 63, w = t >> 6;
    const int c16 = lane & 15, g = lane >> 4;
    const int wm  = (w & 1) * 32, wn = (w >> 1) * 32;
    const int lr  = t >> 2, lc = (t & 3) * 8;

    f32x4 acc[2][2] = {};

    for (int k0 = 0; k0 < K; k0 += 32) {
        __syncthreads();
        *(short8*)&As[lr][lc] = *(const short8*)(A  + (size_t)(m0 + lr) * K + k0 + lc);
        *(short8*)&Bs[lr][lc] = *(const short8*)(BT + (size_t)(n0 + lr) * K + k0 + lc);
        __syncthreads();

        short8 af[2], bf[2];
        #pragma unroll
        for (int i = 0; i < 2; i++) {
            af[i] = *(const short8*)&As[wm + i * 16 + c16][g * 8];
            bf[i] = *(const short8*)&Bs[wn + i * 16 + c16][g * 8];
        }
        #pragma unroll
        for (int i = 0; i < 2; i++)
            #pragma unroll
            for (int j = 0; j < 2; j++)
                acc[i][j] = __builtin_amdgcn_mfma_f32_16x16x32_bf16(af[i], bf[j], acc[i][j], 0, 0, 0);
    }

    #pragma unroll
    for (int i = 0; i < 2; i++) {
        #pragma unroll
        for (int j = 0; j < 2; j++) {
            #pragma unroll
            for (int r = 0; r < 4; r++) {
                int m = m0 + wm + i * 16 + g * 4 + r;
                int n = n0 + wn + j * 16 + c16;
                float v = acc[i][j][r] * alpha;
                if (mode == 0) {
                    outf[(size_t)m * N + n] = v + (bias ? bias[n] : 0.0f);
                } else {
                    int bb = m >> 11, l = m & 2047;
                    int hh = n >> 5,  cc = n & 31;
                    if (mode == 1)
                        outb[(((size_t)bb * NH + hh) * QL + l) * CH + cc] = f2bf(v);
                    else
                        outb[(((size_t)bb * NH + hh) * CH + cc) * (size_t)KVL + l] = f2bf(v);
                }
            }
        }
    }
}

// ---------------------------------------------------------------------------
// Flash attention, R13: BATCH-SHARED BIAS. Block = (q-tile 32, h) x ALL 4 b.
// 8 waves = 4 b x 2 kv-halves. The 4 b-waves read IDENTICAL bias addresses
// per strip (bias has no b index) -> 3 of 4 hit L1; logical bias stream from
// L3 drops 537 -> 134 MB. K/V staged per-b in LDS (KVB=64, double-buffered);
// mask terms staged once as bf16 (exact: unmasked mt is one constant, masked
// underflows exp2 to 0).
// Per-wave math identical to R12: 32x32x16 MFMA, swapped QK^T (D = K.Q^T:
// lane (l31,hi) reg r = S[kv=(r&3)+8*(r>>2)+4*hi][q=l31]), static-max exp2
// softmax with bias folded into MFMA C-in, in-register P via pkbf +
// v_permlane32_swap. kv-halves combined through LDS at end (additive).
// LDS: Kl 32 KB + Vl 32 KB + Mt 16 KB = 80 KB -> 2 blocks/CU, 4 waves/SIMD.
// ---------------------------------------------------------------------------
__global__ __launch_bounds__(512) void fattn(
    const short* __restrict__ qbf, const short* __restrict__ kbf,
    const short* __restrict__ vtb, const float* __restrict__ mask,
    const float* __restrict__ bias, short* __restrict__ aob)
{
    __shared__ __align__(16) short Kl[2][B][KVB * 32];   // 2 x 16 KB, swizzled [kv][ch]
    __shared__ __align__(16) short Vl[2][B][32 * KVB];   // 2 x 16 KB, swizzled [ch][kv]
    __shared__ __align__(16) short Mt[B][KVL];           // 16 KB bf16 mask terms

    const int t    = threadIdx.x;
    const int wv   = t >> 6;
    const int bq   = wv & 3;          // wave's batch
    const int ws   = wv >> 2;         // wave's kv half (32 of each 64-strip)
    const int lane = t & 63;
    const int l31  = lane & 31;
    const int hi   = lane >> 5;

    const int q0 = blockIdx.x * 32;
    const int h  = blockIdx.y;
    const int bh = bq * NH + h;
    const int ws32 = ws * 32;

    constexpr float L2E  = 1.4426950408889634f;
    constexpr float MBIG = 1e9f * L2E;
    constexpr float MOFF = -(1e9f * L2E) - 40.0f * L2E;  // -MBIG - C (static max)

    // ---- Q fragments: q row = q0 + l31 (32-row tile), ch halves ----
    const short* qrow = qbf + ((size_t)bh * QL + q0 + l31) * CH;
    short8 qf0 = *(const short8*)(qrow + hi * 8);
    short8 qf1 = *(const short8*)(qrow + 16 + hi * 8);

    // ---- mask terms -> Mt (bf16) once per block: thread t: b=t>>7, 16 kv ----
    {
        const int bm = t >> 7, idx = t & 127;
        const float* mp = mask + (size_t)bm * KVL + idx * 16;
        float4 m0 = *(const float4*)(mp);
        float4 m1 = *(const float4*)(mp + 4);
        float4 m2 = *(const float4*)(mp + 8);
        float4 m3 = *(const float4*)(mp + 12);
        short8 s0 = { f2bf(fmaf(m0.x, MBIG, MOFF)), f2bf(fmaf(m0.y, MBIG, MOFF)),
                      f2bf(fmaf(m0.z, MBIG, MOFF)), f2bf(fmaf(m0.w, MBIG, MOFF)),
                      f2bf(fmaf(m1.x, MBIG, MOFF)), f2bf(fmaf(m1.y, MBIG, MOFF)),
                      f2bf(fmaf(m1.z, MBIG, MOFF)), f2bf(fmaf(m1.w, MBIG, MOFF)) };
        short8 s1 = { f2bf(fmaf(m2.x, MBIG, MOFF)), f2bf(fmaf(m2.y, MBIG, MOFF)),
                      f2bf(fmaf(m2.z, MBIG, MOFF)), f2bf(fmaf(m2.w, MBIG, MOFF)),
                      f2bf(fmaf(m3.x, MBIG, MOFF)), f2bf(fmaf(m3.y, MBIG, MOFF)),
                      f2bf(fmaf(m3.z, MBIG, MOFF)), f2bf(fmaf(m3.w, MBIG, MOFF)) };
        *(short8*)&Mt[bm][idx * 16]     = s0;
        *(short8*)&Mt[bm][idx * 16 + 8] = s1;
    }

    // ---- staging addresses: thread t stages 32 B of K and 32 B of V for
    //      batch bk = t>>7 (128 threads per batch section) ----
    const int bk   = t >> 7, ik = t & 127;
    const int krow = ik >> 1, khalf = ik & 1;
    const short* ksrc = kbf + ((size_t)(bk * NH + h) * KVL + krow) * CH + khalf * 16;
    const int kb0 = (krow * 64 + khalf * 32)      ^ ((krow & 7) << 4);
    const int kb1 = (krow * 64 + khalf * 32 + 16) ^ ((krow & 7) << 4);
    const int vrow = ik >> 2, vseg = ik & 3;
    const short* vsrc = vtb + ((size_t)(bk * NH + h) * CH + vrow) * KVL + vseg * 16;
    const int vb0 = (vrow * 128 + vseg * 32)      ^ ((vrow & 7) << 4);
    const int vb1 = (vrow * 128 + vseg * 32 + 16) ^ ((vrow & 7) << 4);

    short8 kr0 = *(const short8*)ksrc;          // prefetch strip 0
    short8 kr1 = *(const short8*)(ksrc + 8);
    short8 vr0 = *(const short8*)vsrc;
    short8 vr1 = *(const short8*)(vsrc + 8);

    // bias row for this lane's q-row (NO b index -> shared by 4 b-waves)
    const float* brow = bias + ((size_t)h * QL + q0 + l31) * KVL;

    // prefetch bias for strip 0 (this wave's kv half)
    float4 biA[4], biB[4];
    #pragma unroll
    for (int rr = 0; rr < 4; ++rr)
        biA[rr] = *(const float4*)(brow + ws32 + rr * 8 + hi * 4);

    const short* mtb = &Mt[bq][0];

    f32x16 O;
    #pragma unroll
    for (int r = 0; r < 16; ++r) O[r] = 0.0f;
    float lp0 = 0.f, lp1 = 0.f, lp2 = 0.f, lp3 = 0.f;

    // One strip (this wave handles its 32-kv half = one 32x32 MFMA sub).
#define STRIP_BODY(IT, BUF, BC, BN)                                            \
    {                                                                          \
        char* kst = (char*)&Kl[BUF][bk][0];                                    \
        char* vst = (char*)&Vl[BUF][bk][0];                                    \
        *(short8*)(kst + kb0) = kr0;  *(short8*)(kst + kb1) = kr1;             \
        *(short8*)(vst + vb0) = vr0;  *(short8*)(vst + vb1) = vr1;             \
        __syncthreads();                                                       \
        if ((IT) + 1 < NSTRIP) {                                               \
            const short* kn = ksrc + (size_t)((IT) + 1) * KVB * CH;            \
            const short* vn = vsrc + ((IT) + 1) * KVB;                         \
            kr0 = *(const short8*)kn;  kr1 = *(const short8*)(kn + 8);         \
            vr0 = *(const short8*)vn;  vr1 = *(const short8*)(vn + 8);         \
            _Pragma("unroll")                                                  \
            for (int rr = 0; rr < 4; ++rr)                                     \
                BN[rr] = *(const float4*)(brow + ((IT) + 1) * KVB + ws32 + rr * 8 + hi * 4); \
        }                                                                      \
        const char* klb = (const char*)&Kl[BUF][bq][0];                        \
        const char* vlb = (const char*)&Vl[BUF][bq][0];                        \
        f32x16 Cb;                                                             \
        _Pragma("unroll")                                                      \
        for (int rr = 0; rr < 4; ++rr) {                                       \
            short4v mt4 = *(const short4v*)(mtb + (IT) * KVB + ws32 + rr * 8 + hi * 4); \
            Cb[4 * rr + 0] = fmaf(BC[rr].x, L2E, bf2f(mt4[0]));                \
            Cb[4 * rr + 1] = fmaf(BC[rr].y, L2E, bf2f(mt4[1]));                \
            Cb[4 * rr + 2] = fmaf(BC[rr].z, L2E, bf2f(mt4[2]));                \
            Cb[4 * rr + 3] = fmaf(BC[rr].w, L2E, bf2f(mt4[3]));                \
        }                                                                      \
        const int krow32 = ws32 + l31;                                         \
        const int kswz   = (krow32 & 7) << 4;                                  \
        short8 ka0 = *(const short8*)(klb + ((krow32 * 64 + hi * 16) ^ kswz)); \
        short8 ka1 = *(const short8*)(klb + ((krow32 * 64 + 32 + hi * 16) ^ kswz)); \
        __builtin_amdgcn_s_setprio(1);                                         \
        f32x16 S = __builtin_amdgcn_mfma_f32_32x32x16_bf16(ka0, qf0, Cb, 0, 0, 0); \
        S = __builtin_amdgcn_mfma_f32_32x32x16_bf16(ka1, qf1, S, 0, 0, 0);     \
        __builtin_amdgcn_s_setprio(0);                                         \
        unsigned int a1, a2, b1, b2, c1, c2, d1, d2;                           \
        {   float e0 = __builtin_amdgcn_exp2f(S[0]);                           \
            float e1 = __builtin_amdgcn_exp2f(S[1]);                           \
            float e2 = __builtin_amdgcn_exp2f(S[2]);                           \
            float e3 = __builtin_amdgcn_exp2f(S[3]);                           \
            lp0 += e0 + e1;  lp1 += e2 + e3;                                   \
            a1 = pkbf(e0, e1);  a2 = pkbf(e2, e3);  }                          \
        {   float e0 = __builtin_amdgcn_exp2f(S[4]);                           \
            float e1 = __builtin_amdgcn_exp2f(S[5]);                           \
            float e2 = __builtin_amdgcn_exp2f(S[6]);                           \
            float e3 = __builtin_amdgcn_exp2f(S[7]);                           \
            lp0 += e0 + e1;  lp1 += e2 + e3;                                   \
            b1 = pkbf(e0, e1);  b2 = pkbf(e2, e3);  }                          \
        {   float e0 = __builtin_amdgcn_exp2f(S[8]);                           \
            float e1 = __builtin_amdgcn_exp2f(S[9]);                           \
            float e2 = __builtin_amdgcn_exp2f(S[10]);                          \
            float e3 = __builtin_amdgcn_exp2f(S[11]);                          \
            lp2 += e0 + e1;  lp3 += e2 + e3;                                   \
            c1 = pkbf(e0, e1);  c2 = pkbf(e2, e3);  }                          \
        {   float e0 = __builtin_amdgcn_exp2f(S[12]);                          \
            float e1 = __builtin_amdgcn_exp2f(S[13]);                          \
            float e2 = __builtin_amdgcn_exp2f(S[14]);                          \
            float e3 = __builtin_amdgcn_exp2f(S[15]);                          \
            lp2 += e0 + e1;  lp3 += e2 + e3;                                   \
            d1 = pkbf(e0, e1);  d2 = pkbf(e2, e3);  }                          \
        asm("v_permlane32_swap_b32 %0, %1" : "+v"(a1), "+v"(b1));              \
        asm("v_permlane32_swap_b32 %0, %1" : "+v"(a2), "+v"(b2));              \
        asm("v_permlane32_swap_b32 %0, %1" : "+v"(c1), "+v"(d1));              \
        asm("v_permlane32_swap_b32 %0, %1" : "+v"(c2), "+v"(d2));              \
        u32x4 f0v = { a1, a2, b1, b2 };                                        \
        u32x4 f1v = { c1, c2, d1, d2 };                                        \
        short8 pf0 = __builtin_bit_cast(short8, f0v);                          \
        short8 pf1 = __builtin_bit_cast(short8, f1v);                          \
        const int vswz = (l31 & 7) << 4;                                       \
        short8 vf0 = *(const short8*)(vlb + ((l31 * 128 + ws * 64 + hi * 16) ^ vswz)); \
        short8 vf1 = *(const short8*)(vlb + ((l31 * 128 + ws * 64 + 32 + hi * 16) ^ vswz)); \
        __builtin_amdgcn_s_setprio(1);                                         \
        O = __builtin_amdgcn_mfma_f32_32x32x16_bf16(pf0, vf0, O, 0, 0, 0);     \
        O = __builtin_amdgcn_mfma_f32_32x32x16_bf16(pf1, vf1, O, 0, 0, 0);     \
        __builtin_amdgcn_s_setprio(0);                                         \
    }

    #pragma unroll 1
    for (int pp = 0; pp < NSTRIP / 2; ++pp) {
        STRIP_BODY(2 * pp,     0, biA, biB);
        STRIP_BODY(2 * pp + 1, 1, biB, biA);
    }
#undef STRIP_BODY

    // ---- combine the two kv-halves through LDS, normalize, store ----
    float lpq = (lp0 + lp1) + (lp2 + lp3);
    lpq += __shfl_xor(lpq, 32);                 // lane l31 holds l (own half) for q=l31

    float* Ob = (float*)&Kl[0][0][0];           // 16 KB: [b][32 q][32 ch]
    float* Lb = (float*)&Vl[0][0][0];           // [b][32]
    __syncthreads();
    if (ws == 1) {
        float* op = Ob + bq * 32 * 32;
        #pragma unroll
        for (int r = 0; r < 16; ++r) {
            int q = (r & 3) + 8 * (r >> 2) + 4 * hi;
            op[q * 32 + l31] = O[r];
        }
        if (lane < 32) Lb[bq * 32 + l31] = lpq;
    }
    __syncthreads();
    if (ws == 0) {
        const float* op = Ob + bq * 32 * 32;
        float ltot = lpq + Lb[bq * 32 + l31];
        float linv = 1.0f / ltot;               // lane l31 <-> q = l31
        short* aop = aob + ((size_t)bq * QL + q0) * DM + h * CH;
        #pragma unroll
        for (int r = 0; r < 16; ++r) {
            int q = (r & 3) + 8 * (r >> 2) + 4 * hi;
            float ov = O[r] + op[q * 32 + l31];
            float inv = __shfl(linv, q);
            aop[(size_t)q * DM + l31] = f2bf(ov * inv);
        }
    }
}

// ---------------------------------------------------------------------------
extern "C" void kernel_launch(void* const* d_in, const int* in_sizes, int n_in,
                              void* d_out, int out_size, void* d_ws, size_t ws_size,
                              hipStream_t stream)
{
    const float* input_q  = (const float*)d_in[0];
    const float* input_kv = (const float*)d_in[1];
    const float* mask     = (const float*)d_in[2];
    const float* bias     = (const float*)d_in[3];
    const float* w_q      = (const float*)d_in[4];
    const float* w_k      = (const float*)d_in[5];
    const float* w_v      = (const float*)d_in[6];
    const float* w_o      = (const float*)d_in[7];
    const float* b_o      = (const float*)d_in[8];
    float* out = (float*)d_out;

    const size_t TOK  = (size_t)B * QL;            // 8192
    const size_t HEAD = (size_t)B * NH * QL * CH;  // 2,097,152 elems

    short* qbf = (short*)d_ws;          // bf16 Q  head-split       4 MB
    short* kbf = qbf + HEAD;            // bf16 K  head-split       4 MB
    short* vtb = kbf + HEAD;            // bf16 V^T head-split      4 MB
    short* aob = vtb + HEAD;            // bf16 attn out [tok][dm]  4 MB
    short* qx  = aob + HEAD;            // bf16 input_q             4 MB
    short* kvx = qx  + HEAD;            // bf16 input_kv            4 MB
    short* wqT = kvx + HEAD;            // bf16 w_q^T  [N][K]       128 KB
    short* wkT = wqT + CQ * DM;
    short* wvT = wkT + CKV * DM;
    short* woT = wvT + CKV * DM;

    dim3 blk(256);
    // 1/sqrt(32) * log2(e): static-max softmax works in exp2 units
    const float qscale = 0.17677669529663687f * 1.4426950408889634f;

    prep_cvt<<<dim3((TOK * CQ / 8 + 255) / 256), blk, 0, stream>>>(input_q,  qx,  (int)(TOK * CQ / 8));
    prep_cvt<<<dim3((TOK * CKV / 8 + 255) / 256), blk, 0, stream>>>(input_kv, kvx, (int)(TOK * CKV / 8));
    prep_wT<<<dim3(DM / 32, CQ / 32),  blk, 0, stream>>>(w_q, wqT, CQ,  DM);
    prep_wT<<<dim3(DM / 32, CKV / 32), blk, 0, stream>>>(w_k, wkT, CKV, DM);
    prep_wT<<<dim3(DM / 32, CKV / 32), blk, 0, stream>>>(w_v, wvT, CKV, DM);
    prep_wT<<<dim3(CQ / 32, DM / 32),  blk, 0, stream>>>(w_o, woT, DM,  CQ);

    dim3 pgrid(DM / 64, TOK / 64);                 // (4, 128)
    gemm_mfma<<<pgrid, blk, 0, stream>>>(qx,  wqT, nullptr, nullptr, qbf,
                                         (int)TOK, DM, CQ,  qscale, 1);
    gemm_mfma<<<pgrid, blk, 0, stream>>>(kvx, wkT, nullptr, nullptr, kbf,
                                         (int)TOK, DM, CKV, 1.0f, 1);
    gemm_mfma<<<pgrid, blk, 0, stream>>>(kvx, wvT, nullptr, nullptr, vtb,
                                         (int)TOK, DM, CKV, 1.0f, 2);

    fattn<<<dim3(QL / 32, NH), dim3(512), 0, stream>>>(
        qbf, kbf, vtb, mask, bias, aob);

    gemm_mfma<<<dim3(CQ / 64, TOK / 64), blk, 0, stream>>>(aob, woT, b_o, out, nullptr,
                                         (int)TOK, CQ, DM, 1.0f, 0);
}